// Round 6
// baseline (115.208 us; speedup 1.0000x reference)
//
#include <hip/hip_runtime.h>
#include <hip/hip_bf16.h>

// Problem constants
#define Bc 2
#define Nc 6
#define Cc 64
#define Hc 28
#define Wc 50
#define Dc 59
#define BHc 200
#define BWc 200
// BEV_X0 = BEV_Y0 = -50.0, RES = 0.5

#define DSPLIT 4          // blocks per (b,n,w) along d
#define DCHUNK 16         // d slots per block (4*16=64 >= 59, guarded)
#define DWAVE 4           // d's per wave (4 waves x 4 = 16)

#define HWc (Hc * Wc)     // 1400
#define NT1 (Bc * Nc * 22)        // feat tiles: ceil(1400/64)=22 per (b,n)
#define NT2 (Bc * Nc * Dc)        // depth planes: 708
#define NZ  640                   // acc-zero blocks
#define ACC_ELEMS ((size_t)Bc * BHc * BWc * Cc)   // 5,120,000 floats

// ---------------------------------------------------------------------------
// Fused: feats (B,N,C,H,W) -> F' (B,N,H,W,C); depth (B,N,D,H,W) -> D'' (B,N,D,W,H);
// plus grid-stride zeroing of acc (saves a separate memset dispatch).
__global__ __launch_bounds__(256) void fp_pretrans(
    const float* __restrict__ feats,
    const float* __restrict__ depth,
    float* __restrict__ Fp,            // (B,N,H,W,C)
    float* __restrict__ Dpp,           // (B,N,D,W,H)
    float* __restrict__ acc)           // zeroed here
{
    __shared__ float t[64][65];
    __shared__ float t2[Hc][Wc + 1];

    int bid = blockIdx.x;
    int tid = threadIdx.x;

    if (bid < NT1) {
        // feat tile: (c, hw) -> (hw, c), 64 x 64 tile
        int bn  = bid / 22;
        int hw0 = (bid % 22) * 64;
        int tx = tid & 63;
        int ty = tid >> 6;
        const float* src = feats + (size_t)bn * Cc * HWc;
        float* dst = Fp + (size_t)bn * HWc * Cc;
#pragma unroll
        for (int i = 0; i < 16; ++i) {
            int c = ty * 16 + i;
            int hw = hw0 + tx;
            t[c][tx] = (hw < HWc) ? src[(size_t)c * HWc + hw] : 0.0f;
        }
        __syncthreads();
#pragma unroll
        for (int i = 0; i < 16; ++i) {
            int j = ty * 16 + i;                 // hw-local
            if (hw0 + j < HWc)
                dst[(size_t)(hw0 + j) * Cc + tx] = t[tx][j];
        }
    } else if (bid < NT1 + NT2) {
        // depth plane: (h,w) -> (w,h) within plane (b,n,d)
        int bid2 = bid - NT1;
        int bn = bid2 / Dc;
        int d  = bid2 % Dc;
        const float* sp = depth + ((size_t)bn * Dc + d) * HWc;
        float* dp = Dpp + ((size_t)bn * Dc + d) * HWc;
        for (int idx = tid; idx < HWc; idx += 256)
            t2[idx / Wc][idx % Wc] = sp[idx];
        __syncthreads();
        for (int idx = tid; idx < HWc; idx += 256) {
            int w = idx / Hc, h = idx % Hc;
            dp[idx] = t2[h][w];
        }
    } else {
        // zero acc: float4 grid-stride
        const size_t NF4 = ACC_ELEMS / 4;        // 1,280,000
        float4* a4 = (float4*)acc;
        size_t base = (size_t)(bid - NT1 - NT2) * 2048;
#pragma unroll
        for (int it = 0; it < 8; ++it) {
            size_t i = base + (size_t)it * 256 + tid;
            if (i < NF4) a4[i] = make_float4(0.f, 0.f, 0.f, 0.f);
        }
    }
}

// ---------------------------------------------------------------------------
// Scatter v5: block per (b,n,w,dq). lane = channel c. NO mdep LDS:
// masked depth stays in lane-h registers; phase 2 broadcasts via v_readlane
// (SALU path, no LDS traffic). FMA order identical to v4 (bit-stable).
__global__ __launch_bounds__(256) void fp_scatter5(
    const float* __restrict__ Fp,      // (B,N,H,W,C)
    const float* __restrict__ Dpp,     // (B,N,D,W,H)
    const float* __restrict__ Kmat,    // (B,N,3,3)
    const float* __restrict__ Emat,    // (B,N,4,4)
    float* __restrict__ acc)           // (B, BH*BW, C)
{
    __shared__ __align__(16) float feat_lds[Hc][Cc];   // [h][c]

    int bid = blockIdx.x;
    int dq  = bid & (DSPLIT - 1);
    int pix = bid >> 2;                  // (b*N + n)*W + w
    int w  = pix % Wc;
    int bn = pix / Wc;
    int b  = bn / Nc;
    int tid  = threadIdx.x;
    int lane = tid & 63;
    int wid  = tid >> 6;

    // Phase 0: stage feat column, coalesced
    const float* fbase = Fp + ((size_t)bn * Hc * Wc + w) * Cc;
    for (int hh = wid; hh < Hc; hh += 4)
        feat_lds[hh][lane] = fbase[(size_t)hh * Wc * Cc + lane];

    // ---- K inverse (f32 adjugate, correctly-rounded division) ----
    const float* K = Kmat + (size_t)bn * 9;
    float k00 = K[0], k01 = K[1], k02 = K[2];
    float k10 = K[3], k11 = K[4], k12 = K[5];
    float k20 = K[6], k21 = K[7], k22 = K[8];

    float c00 = __fsub_rn(__fmul_rn(k11, k22), __fmul_rn(k12, k21));
    float c01 = __fsub_rn(__fmul_rn(k12, k20), __fmul_rn(k10, k22));
    float c02 = __fsub_rn(__fmul_rn(k10, k21), __fmul_rn(k11, k20));
    float det = __fadd_rn(__fadd_rn(__fmul_rn(k00, c00), __fmul_rn(k01, c01)),
                          __fmul_rn(k02, c02));
    float i00 = __fdiv_rn(c00, det);
    float i01 = __fdiv_rn(__fsub_rn(__fmul_rn(k02, k21), __fmul_rn(k01, k22)), det);
    float i02 = __fdiv_rn(__fsub_rn(__fmul_rn(k01, k12), __fmul_rn(k02, k11)), det);
    float i10 = __fdiv_rn(c01, det);
    float i11 = __fdiv_rn(__fsub_rn(__fmul_rn(k00, k22), __fmul_rn(k02, k20)), det);
    float i12 = __fdiv_rn(__fsub_rn(__fmul_rn(k02, k10), __fmul_rn(k00, k12)), det);
    float i20 = __fdiv_rn(c02, det);
    float i21 = __fdiv_rn(__fsub_rn(__fmul_rn(k01, k20), __fmul_rn(k00, k21)), det);
    float i22 = __fdiv_rn(__fsub_rn(__fmul_rn(k00, k11), __fmul_rn(k01, k10)), det);

    const float* E = Emat + (size_t)bn * 16;
    float r00 = E[0], r01 = E[1], r02 = E[2],  tx = E[3];
    float r10 = E[4], r11 = E[5], r12 = E[6],  ty = E[7];
    float r20 = E[8], r21 = E[9], r22 = E[10], tz = E[11];

    __syncthreads();   // feat_lds ready (fallback may read any h)

    float* accb = acc + (size_t)b * (BHc * BWc) * Cc;

    int h = lane;                        // geometry lane role
    float xf = (float)w;
    float yf = (float)h;
    int ld0 = wid * DWAVE;

    float accv[DWAVE];
    float mval[DWAVE];                   // masked depth, lane h slot k
    int   prim[DWAVE];

    // ---- Phase 1: geometry; masked depth kept in registers ----
#pragma unroll
    for (int k = 0; k < DWAVE; ++k) {
        accv[k] = 0.0f;
        mval[k] = 0.0f;
        prim[k] = -1;
        int ld = ld0 + k;
        int dg = dq * DCHUNK + ld;
        if (dg < Dc) {
            float db = (float)(dg + 1);          // depth bins 1..59
            float dep = 0.0f;
            if (h < Hc)
                dep = Dpp[(((size_t)bn * Dc + dg) * Wc + w) * Hc + h];

            float px = __fmul_rn(xf, db);
            float py = __fmul_rn(yf, db);
            float pz = db;

            float cx = __fadd_rn(__fadd_rn(__fmul_rn(i00, px), __fmul_rn(i01, py)), __fmul_rn(i02, pz));
            float cy = __fadd_rn(__fadd_rn(__fmul_rn(i10, px), __fmul_rn(i11, py)), __fmul_rn(i12, pz));
            float cz = __fadd_rn(__fadd_rn(__fmul_rn(i20, px), __fmul_rn(i21, py)), __fmul_rn(i22, pz));

            float ex = __fadd_rn(__fadd_rn(__fadd_rn(__fmul_rn(r00, cx), __fmul_rn(r01, cy)), __fmul_rn(r02, cz)), tx);
            float ey = __fadd_rn(__fadd_rn(__fadd_rn(__fmul_rn(r10, cx), __fmul_rn(r11, cy)), __fmul_rn(r12, cz)), ty);
            float ez = __fadd_rn(__fadd_rn(__fadd_rn(__fmul_rn(r20, cx), __fmul_rn(r21, cy)), __fmul_rn(r22, cz)), tz);

            int bx = (int)(__fmul_rn(__fadd_rn(ex, 50.0f), 2.0f));
            int by = (int)(__fmul_rn(__fadd_rn(ey, 50.0f), 2.0f));

            bool valid = (h < Hc) & (bx >= 0) & (bx < BWc) & (by >= 0) & (by < BHc) & (ez > 0.0f);
            int binidx = by * BWc + bx;

            unsigned long long vm = __ballot(valid);
            if (vm != 0ULL) {
                int first = __builtin_ctzll(vm);
                int pr = __shfl(binidx, first);
                unsigned long long match = __ballot(valid && (binidx == pr));
                unsigned long long rest  = vm & ~match;
                prim[k] = pr;
                mval[k] = (valid && (binidx == pr)) ? dep : 0.0f;

                // fallback: valid h with a different bin (general case)
                while (rest) {
                    int hh2 = __builtin_ctzll(rest);
                    rest &= rest - 1;
                    int   bidx = __shfl(binidx, hh2);
                    float dv   = __shfl(dep, hh2);
                    atomicAdd(&accb[(size_t)bidx * Cc + lane],
                              __fmul_rn(feat_lds[hh2][lane], dv));
                }
            }
        }
    }

    // ---- Phase 2: dense matmul, depth broadcast via readlane (no LDS) ----
#pragma unroll
    for (int hh = 0; hh < Hc; ++hh) {
        float f = feat_lds[hh][lane];
        float d0 = __int_as_float(__builtin_amdgcn_readlane(__float_as_int(mval[0]), hh));
        float d1 = __int_as_float(__builtin_amdgcn_readlane(__float_as_int(mval[1]), hh));
        float d2 = __int_as_float(__builtin_amdgcn_readlane(__float_as_int(mval[2]), hh));
        float d3 = __int_as_float(__builtin_amdgcn_readlane(__float_as_int(mval[3]), hh));
        accv[0] = __builtin_fmaf(f, d0, accv[0]);
        accv[1] = __builtin_fmaf(f, d1, accv[1]);
        accv[2] = __builtin_fmaf(f, d2, accv[2]);
        accv[3] = __builtin_fmaf(f, d3, accv[3]);
    }

    // ---- Phase 3: one 64-lane atomic per d ----
#pragma unroll
    for (int k = 0; k < DWAVE; ++k) {
        if (prim[k] >= 0)
            atomicAdd(&accb[(size_t)prim[k] * Cc + lane], accv[k]);
    }
}

// (B, BH*BW, C) -> (B, C, BH*BW), LDS-tiled 64x64
__global__ __launch_bounds__(256) void fp_transpose_kernel(
    const float* __restrict__ acc, float* __restrict__ out)
{
    __shared__ float tile[64][65];
    const int P = BHc * BWc;                 // 40000, divisible by 64
    int b = blockIdx.y;
    int p0 = blockIdx.x * 64;
    int tx = threadIdx.x & 63;
    int ty = threadIdx.x >> 6;               // 0..3

    const float* src = acc + (size_t)b * P * Cc;
#pragma unroll
    for (int i = 0; i < 16; ++i) {
        int row = ty * 16 + i;
        tile[row][tx] = src[(size_t)(p0 + row) * Cc + tx];
    }
    __syncthreads();
    float* dst = out + (size_t)b * Cc * P;
#pragma unroll
    for (int i = 0; i < 16; ++i) {
        int c = ty * 16 + i;
        dst[(size_t)c * P + p0 + tx] = tile[tx][c];
    }
}

extern "C" void kernel_launch(void* const* d_in, const int* in_sizes, int n_in,
                              void* d_out, int out_size, void* d_ws, size_t ws_size,
                              hipStream_t stream) {
    const float* feats = (const float*)d_in[0];
    const float* depth = (const float*)d_in[1];
    const float* Kmat  = (const float*)d_in[2];
    const float* Emat  = (const float*)d_in[3];
    float* out = (float*)d_out;

    const size_t F_ELEMS = (size_t)Bc * Nc * Hc * Wc * Cc;  // 1,075,200
    const size_t D_ELEMS = (size_t)Bc * Nc * Dc * Hc * Wc;  //   991,200

    float* acc  = (float*)d_ws;
    float* Fp   = acc + ACC_ELEMS;
    float* Dpp  = Fp + F_ELEMS;
    float* acc2 = Dpp + D_ELEMS;   // dummy target for attribution duplicate

    // 1) fused transpose + acc-zero
    fp_pretrans<<<NT1 + NT2 + NZ, 256, 0, stream>>>(feats, depth, Fp, Dpp, acc);

    // 2) scatter (real) + duplicate into dummy region (timing attribution)
    const int NBLK = Bc * Nc * Wc * DSPLIT;  // 2400
    fp_scatter5<<<NBLK, 256, 0, stream>>>(Fp, Dpp, Kmat, Emat, acc);
    fp_scatter5<<<NBLK, 256, 0, stream>>>(Fp, Dpp, Kmat, Emat, acc2);

    // 3) transpose to output layout
    fp_transpose_kernel<<<dim3((BHc * BWc) / 64, Bc), 256, 0, stream>>>(acc, out);
}

// Round 7
// 107.210 us; speedup vs baseline: 1.0746x; 1.0746x over previous
//
#include <hip/hip_runtime.h>
#include <hip/hip_bf16.h>

// Problem constants
#define Bc 2
#define Nc 6
#define Cc 64
#define Hc 28
#define Wc 50
#define Dc 59
#define BHc 200
#define BWc 200
// BEV_X0 = BEV_Y0 = -50.0, RES = 0.5

#define DSPLIT 4          // blocks per (b,n,w) along d
#define DCHUNK 16         // d slots per block (4*16=64 >= 59, guarded)
#define DWAVE 4           // d's per wave (4 waves x 4 = 16)

#define HWc (Hc * Wc)     // 1400
#define HW4 (HWc / 4)     // 350 float4 per plane/row-block
#define NT1 (Bc * Nc * 22)        // feat tiles: ceil(1400/64)=22 per (b,n)
#define NPLANES (Bc * Nc * Dc)    // 708 depth planes
#define DP_GROUP 4
#define NT2g ((NPLANES + DP_GROUP - 1) / DP_GROUP)   // 177
#define NZ  640                   // acc-zero blocks
#define ACC_ELEMS ((size_t)Bc * BHc * BWc * Cc)   // 5,120,000 floats

// ---------------------------------------------------------------------------
// Pre-transpose v2 (all-float4 global I/O):
//   feats (B,N,C,H,W) -> F' (B,N,H,W,C)     [64c x 64hw tiles]
//   depth (B,N,D,H,W) -> D'' (B,N,D,W,H)    [4 planes per block]
//   + grid-stride zeroing of acc
__global__ __launch_bounds__(256) void fp_pretrans(
    const float* __restrict__ feats,
    const float* __restrict__ depth,
    float* __restrict__ Fp,            // (B,N,H,W,C)
    float* __restrict__ Dpp,           // (B,N,D,W,H)
    float* __restrict__ acc)           // zeroed here
{
    __shared__ float t[64][65];                 // feat tile [c][hw-local]
    __shared__ float t2m[DP_GROUP][Hc][Wc + 1]; // depth planes [h][w]

    int bid = blockIdx.x;
    int tid = threadIdx.x;

    if (bid < NT1) {
        // ---- feat tile: (c, hw) -> (hw, c) ----
        int bn  = bid / 22;
        int hw0 = (bid % 22) * 64;
        int nq  = (hw0 + 64 <= HWc) ? 16 : (HWc - hw0) / 4;   // 16 or 14
        const float4* src4 = (const float4*)(feats + (size_t)bn * Cc * HWc);
        float4* dst4 = (float4*)(Fp + (size_t)bn * HWc * Cc);

        int q  = tid & 15;          // float4 slot within tile row
        int cg = tid >> 4;          // c group
#pragma unroll
        for (int i = 0; i < 4; ++i) {
            int c = cg + i * 16;
            if (q < nq) {
                float4 v = src4[(size_t)c * HW4 + (hw0 >> 2) + q];
                t[c][q * 4 + 0] = v.x;
                t[c][q * 4 + 1] = v.y;
                t[c][q * 4 + 2] = v.z;
                t[c][q * 4 + 3] = v.w;
            }
        }
        __syncthreads();
        int cq = tid & 15;          // c quad
        int hg = tid >> 4;          // hw-local group
#pragma unroll
        for (int i = 0; i < 4; ++i) {
            int hwl = hg + i * 16;
            if (hwl < nq * 4) {
                float4 v = make_float4(t[cq * 4 + 0][hwl], t[cq * 4 + 1][hwl],
                                       t[cq * 4 + 2][hwl], t[cq * 4 + 3][hwl]);
                dst4[(size_t)(hw0 + hwl) * 16 + cq] = v;
            }
        }
    } else if (bid < NT1 + NT2g) {
        // ---- depth planes: (h,w) -> (w,h), 4 planes per block ----
        int p0 = (bid - NT1) * DP_GROUP;
        const float4* sp4 = (const float4*)depth;
        float4* dp4 = (float4*)Dpp;
#pragma unroll
        for (int pp = 0; pp < DP_GROUP; ++pp) {
            int p = p0 + pp;
            if (p < NPLANES) {
                for (int i4 = tid; i4 < HW4; i4 += 256) {
                    float4 v = sp4[(size_t)p * HW4 + i4];
                    int idx = i4 * 4;
                    t2m[pp][(idx + 0) / Wc][(idx + 0) % Wc] = v.x;
                    t2m[pp][(idx + 1) / Wc][(idx + 1) % Wc] = v.y;
                    t2m[pp][(idx + 2) / Wc][(idx + 2) % Wc] = v.z;
                    t2m[pp][(idx + 3) / Wc][(idx + 3) % Wc] = v.w;
                }
            }
        }
        __syncthreads();
#pragma unroll
        for (int pp = 0; pp < DP_GROUP; ++pp) {
            int p = p0 + pp;
            if (p < NPLANES) {
                for (int i4 = tid; i4 < HW4; i4 += 256) {
                    int w = i4 / 7, h0 = (i4 % 7) * 4;   // 28/4 = 7 quads per w
                    float4 v = make_float4(t2m[pp][h0 + 0][w], t2m[pp][h0 + 1][w],
                                           t2m[pp][h0 + 2][w], t2m[pp][h0 + 3][w]);
                    dp4[(size_t)p * HW4 + i4] = v;
                }
            }
        }
    } else {
        // ---- zero acc: float4 grid-stride ----
        const size_t NF4 = ACC_ELEMS / 4;        // 1,280,000
        float4* a4 = (float4*)acc;
        size_t base = (size_t)(bid - NT1 - NT2g) * 2048;
#pragma unroll
        for (int it = 0; it < 8; ++it) {
            size_t i = base + (size_t)it * 256 + tid;
            if (i < NF4) a4[i] = make_float4(0.f, 0.f, 0.f, 0.f);
        }
    }
}

// ---------------------------------------------------------------------------
// Scatter v5 (unchanged, bit-exact): block per (b,n,w,dq). lane = channel c.
// Masked depth in lane-h registers; phase 2 broadcast via v_readlane.
__global__ __launch_bounds__(256) void fp_scatter5(
    const float* __restrict__ Fp,      // (B,N,H,W,C)
    const float* __restrict__ Dpp,     // (B,N,D,W,H)
    const float* __restrict__ Kmat,    // (B,N,3,3)
    const float* __restrict__ Emat,    // (B,N,4,4)
    float* __restrict__ acc)           // (B, BH*BW, C)
{
    __shared__ __align__(16) float feat_lds[Hc][Cc];   // [h][c]

    int bid = blockIdx.x;
    int dq  = bid & (DSPLIT - 1);
    int pix = bid >> 2;                  // (b*N + n)*W + w
    int w  = pix % Wc;
    int bn = pix / Wc;
    int b  = bn / Nc;
    int tid  = threadIdx.x;
    int lane = tid & 63;
    int wid  = tid >> 6;

    // Phase 0: stage feat column, coalesced
    const float* fbase = Fp + ((size_t)bn * Hc * Wc + w) * Cc;
    for (int hh = wid; hh < Hc; hh += 4)
        feat_lds[hh][lane] = fbase[(size_t)hh * Wc * Cc + lane];

    // ---- K inverse (f32 adjugate, correctly-rounded division) ----
    const float* K = Kmat + (size_t)bn * 9;
    float k00 = K[0], k01 = K[1], k02 = K[2];
    float k10 = K[3], k11 = K[4], k12 = K[5];
    float k20 = K[6], k21 = K[7], k22 = K[8];

    float c00 = __fsub_rn(__fmul_rn(k11, k22), __fmul_rn(k12, k21));
    float c01 = __fsub_rn(__fmul_rn(k12, k20), __fmul_rn(k10, k22));
    float c02 = __fsub_rn(__fmul_rn(k10, k21), __fmul_rn(k11, k20));
    float det = __fadd_rn(__fadd_rn(__fmul_rn(k00, c00), __fmul_rn(k01, c01)),
                          __fmul_rn(k02, c02));
    float i00 = __fdiv_rn(c00, det);
    float i01 = __fdiv_rn(__fsub_rn(__fmul_rn(k02, k21), __fmul_rn(k01, k22)), det);
    float i02 = __fdiv_rn(__fsub_rn(__fmul_rn(k01, k12), __fmul_rn(k02, k11)), det);
    float i10 = __fdiv_rn(c01, det);
    float i11 = __fdiv_rn(__fsub_rn(__fmul_rn(k00, k22), __fmul_rn(k02, k20)), det);
    float i12 = __fdiv_rn(__fsub_rn(__fmul_rn(k02, k10), __fmul_rn(k00, k12)), det);
    float i20 = __fdiv_rn(c02, det);
    float i21 = __fdiv_rn(__fsub_rn(__fmul_rn(k01, k20), __fmul_rn(k00, k21)), det);
    float i22 = __fdiv_rn(__fsub_rn(__fmul_rn(k00, k11), __fmul_rn(k01, k10)), det);

    const float* E = Emat + (size_t)bn * 16;
    float r00 = E[0], r01 = E[1], r02 = E[2],  tx = E[3];
    float r10 = E[4], r11 = E[5], r12 = E[6],  ty = E[7];
    float r20 = E[8], r21 = E[9], r22 = E[10], tz = E[11];

    __syncthreads();   // feat_lds ready (fallback may read any h)

    float* accb = acc + (size_t)b * (BHc * BWc) * Cc;

    int h = lane;                        // geometry lane role
    float xf = (float)w;
    float yf = (float)h;
    int ld0 = wid * DWAVE;

    float accv[DWAVE];
    float mval[DWAVE];                   // masked depth, lane h slot k
    int   prim[DWAVE];

    // ---- Phase 1: geometry; masked depth kept in registers ----
#pragma unroll
    for (int k = 0; k < DWAVE; ++k) {
        accv[k] = 0.0f;
        mval[k] = 0.0f;
        prim[k] = -1;
        int ld = ld0 + k;
        int dg = dq * DCHUNK + ld;
        if (dg < Dc) {
            float db = (float)(dg + 1);          // depth bins 1..59
            float dep = 0.0f;
            if (h < Hc)
                dep = Dpp[(((size_t)bn * Dc + dg) * Wc + w) * Hc + h];

            float px = __fmul_rn(xf, db);
            float py = __fmul_rn(yf, db);
            float pz = db;

            float cx = __fadd_rn(__fadd_rn(__fmul_rn(i00, px), __fmul_rn(i01, py)), __fmul_rn(i02, pz));
            float cy = __fadd_rn(__fadd_rn(__fmul_rn(i10, px), __fmul_rn(i11, py)), __fmul_rn(i12, pz));
            float cz = __fadd_rn(__fadd_rn(__fmul_rn(i20, px), __fmul_rn(i21, py)), __fmul_rn(i22, pz));

            float ex = __fadd_rn(__fadd_rn(__fadd_rn(__fmul_rn(r00, cx), __fmul_rn(r01, cy)), __fmul_rn(r02, cz)), tx);
            float ey = __fadd_rn(__fadd_rn(__fadd_rn(__fmul_rn(r10, cx), __fmul_rn(r11, cy)), __fmul_rn(r12, cz)), ty);
            float ez = __fadd_rn(__fadd_rn(__fadd_rn(__fmul_rn(r20, cx), __fmul_rn(r21, cy)), __fmul_rn(r22, cz)), tz);

            int bx = (int)(__fmul_rn(__fadd_rn(ex, 50.0f), 2.0f));
            int by = (int)(__fmul_rn(__fadd_rn(ey, 50.0f), 2.0f));

            bool valid = (h < Hc) & (bx >= 0) & (bx < BWc) & (by >= 0) & (by < BHc) & (ez > 0.0f);
            int binidx = by * BWc + bx;

            unsigned long long vm = __ballot(valid);
            if (vm != 0ULL) {
                int first = __builtin_ctzll(vm);
                int pr = __shfl(binidx, first);
                unsigned long long match = __ballot(valid && (binidx == pr));
                unsigned long long rest  = vm & ~match;
                prim[k] = pr;
                mval[k] = (valid && (binidx == pr)) ? dep : 0.0f;

                // fallback: valid h with a different bin (general case)
                while (rest) {
                    int hh2 = __builtin_ctzll(rest);
                    rest &= rest - 1;
                    int   bidx = __shfl(binidx, hh2);
                    float dv   = __shfl(dep, hh2);
                    atomicAdd(&accb[(size_t)bidx * Cc + lane],
                              __fmul_rn(feat_lds[hh2][lane], dv));
                }
            }
        }
    }

    // ---- Phase 2: dense matmul, depth broadcast via readlane (no LDS) ----
#pragma unroll
    for (int hh = 0; hh < Hc; ++hh) {
        float f = feat_lds[hh][lane];
        float d0 = __int_as_float(__builtin_amdgcn_readlane(__float_as_int(mval[0]), hh));
        float d1 = __int_as_float(__builtin_amdgcn_readlane(__float_as_int(mval[1]), hh));
        float d2 = __int_as_float(__builtin_amdgcn_readlane(__float_as_int(mval[2]), hh));
        float d3 = __int_as_float(__builtin_amdgcn_readlane(__float_as_int(mval[3]), hh));
        accv[0] = __builtin_fmaf(f, d0, accv[0]);
        accv[1] = __builtin_fmaf(f, d1, accv[1]);
        accv[2] = __builtin_fmaf(f, d2, accv[2]);
        accv[3] = __builtin_fmaf(f, d3, accv[3]);
    }

    // ---- Phase 3: one 64-lane atomic per d ----
#pragma unroll
    for (int k = 0; k < DWAVE; ++k) {
        if (prim[k] >= 0)
            atomicAdd(&accb[(size_t)prim[k] * Cc + lane], accv[k]);
    }
}

// (B, BH*BW, C) -> (B, C, BH*BW), LDS-tiled 64x64
__global__ __launch_bounds__(256) void fp_transpose_kernel(
    const float* __restrict__ acc, float* __restrict__ out)
{
    __shared__ float tile[64][65];
    const int P = BHc * BWc;                 // 40000, divisible by 64
    int b = blockIdx.y;
    int p0 = blockIdx.x * 64;
    int tx = threadIdx.x & 63;
    int ty = threadIdx.x >> 6;               // 0..3

    const float* src = acc + (size_t)b * P * Cc;
#pragma unroll
    for (int i = 0; i < 16; ++i) {
        int row = ty * 16 + i;
        tile[row][tx] = src[(size_t)(p0 + row) * Cc + tx];
    }
    __syncthreads();
    float* dst = out + (size_t)b * Cc * P;
#pragma unroll
    for (int i = 0; i < 16; ++i) {
        int c = ty * 16 + i;
        dst[(size_t)c * P + p0 + tx] = tile[tx][c];
    }
}

extern "C" void kernel_launch(void* const* d_in, const int* in_sizes, int n_in,
                              void* d_out, int out_size, void* d_ws, size_t ws_size,
                              hipStream_t stream) {
    const float* feats = (const float*)d_in[0];
    const float* depth = (const float*)d_in[1];
    const float* Kmat  = (const float*)d_in[2];
    const float* Emat  = (const float*)d_in[3];
    float* out = (float*)d_out;

    const size_t F_ELEMS = (size_t)Bc * Nc * Hc * Wc * Cc;  // 1,075,200
    const size_t D_ELEMS = (size_t)Bc * Nc * Dc * Hc * Wc;  //   991,200

    float* acc  = (float*)d_ws;
    float* Fp   = acc + ACC_ELEMS;
    float* Dpp  = Fp + F_ELEMS;
    float* acc2 = Dpp + D_ELEMS;          // dummy set for attribution dup
    float* Fp2  = acc2 + ACC_ELEMS;
    float* Dpp2 = Fp2 + F_ELEMS;

    const int NPRE = NT1 + NT2g + NZ;     // 264 + 177 + 640 = 1081

    // 1) fused transpose + acc-zero (real) + duplicate (timing attribution)
    fp_pretrans<<<NPRE, 256, 0, stream>>>(feats, depth, Fp, Dpp, acc);
    fp_pretrans<<<NPRE, 256, 0, stream>>>(feats, depth, Fp2, Dpp2, acc2);

    // 2) scatter
    const int NBLK = Bc * Nc * Wc * DSPLIT;  // 2400
    fp_scatter5<<<NBLK, 256, 0, stream>>>(Fp, Dpp, Kmat, Emat, acc);

    // 3) transpose to output layout
    fp_transpose_kernel<<<dim3((BHc * BWc) / 64, Bc), 256, 0, stream>>>(acc, out);
}

// Round 8
// 97.088 us; speedup vs baseline: 1.1866x; 1.1043x over previous
//
#include <hip/hip_runtime.h>
#include <hip/hip_bf16.h>

// Problem constants
#define Bc 2
#define Nc 6
#define Cc 64
#define Hc 28
#define Wc 50
#define Dc 59
#define BHc 200
#define BWc 200
// BEV_X0 = BEV_Y0 = -50.0, RES = 0.5

#define HWc (Hc * Wc)     // 1400
#define NWAVES 8          // 512 threads
#define DWAVE 8           // d's per wave: dg = wid + 8*k, k<8 (64 slots >= 59)
#define NZ 640
#define ACC_ELEMS ((size_t)Bc * BHc * BWc * Cc)   // 5,120,000 floats

// ---------------------------------------------------------------------------
__global__ __launch_bounds__(256) void fp_zero(float* __restrict__ acc)
{
    const size_t NF4 = ACC_ELEMS / 4;            // 1,280,000
    float4* a4 = (float4*)acc;
    size_t base = (size_t)blockIdx.x * 2048;
#pragma unroll
    for (int it = 0; it < 8; ++it) {
        size_t i = base + (size_t)it * 256 + threadIdx.x;
        if (i < NF4) a4[i] = make_float4(0.f, 0.f, 0.f, 0.f);
    }
}

// ---------------------------------------------------------------------------
// Scatter v6: reads ORIGINAL feats/depth layouts (no pretranspose).
// 600 blocks of 512 threads; XCD-swizzled so each XCD's blocks cover <=2
// (b,n) groups (inputs stay L2-resident per XCD). lane = channel c;
// geometry lane role h = lane. Wave wid owns d = wid + 8k.
// Phase 2 broadcasts masked depth via v_readlane (no LDS). Bit-exact
// reference f32 chains; fallback atomic for non-primary bins.
__global__ __launch_bounds__(512) void fp_scatter6(
    const float* __restrict__ feats,   // (B,N,C,H,W)
    const float* __restrict__ depth,   // (B,N,D,H,W)
    const float* __restrict__ Kmat,    // (B,N,3,3)
    const float* __restrict__ Emat,    // (B,N,4,4)
    float* __restrict__ acc)           // (B, BH*BW, C)
{
    __shared__ __align__(16) float feat_lds[Hc][Cc];   // [h][c]

    // XCD-aware swizzle: xcd ~ bid&7 hosts linear range [75*xcd, 75*xcd+75)
    int bid = blockIdx.x;
    int L   = (bid & 7) * 75 + (bid >> 3);   // bijective on [0,600)
    int w   = L % Wc;
    int bn  = L / Wc;
    int b   = bn / Nc;
    int tid  = threadIdx.x;
    int lane = tid & 63;
    int wid  = tid >> 6;                 // 0..7

    const size_t HW = (size_t)HWc;
    const float* fbase = feats + (size_t)bn * Cc * HW + w;
    const float* dcol  = depth + (size_t)bn * Dc * HW + w;

    // Stage feat column: feat_lds[h][c] = feats[b,n,c,h,w] (strided gather,
    // lines shared across the 16 w-neighbor blocks on the same XCD -> L2 hits)
    for (int hh = wid; hh < Hc; hh += NWAVES)
        feat_lds[hh][lane] = fbase[(size_t)lane * HW + (size_t)hh * Wc];

    // ---- K inverse (f32 adjugate, correctly-rounded division) ----
    const float* K = Kmat + (size_t)bn * 9;
    float k00 = K[0], k01 = K[1], k02 = K[2];
    float k10 = K[3], k11 = K[4], k12 = K[5];
    float k20 = K[6], k21 = K[7], k22 = K[8];

    float c00 = __fsub_rn(__fmul_rn(k11, k22), __fmul_rn(k12, k21));
    float c01 = __fsub_rn(__fmul_rn(k12, k20), __fmul_rn(k10, k22));
    float c02 = __fsub_rn(__fmul_rn(k10, k21), __fmul_rn(k11, k20));
    float det = __fadd_rn(__fadd_rn(__fmul_rn(k00, c00), __fmul_rn(k01, c01)),
                          __fmul_rn(k02, c02));
    float i00 = __fdiv_rn(c00, det);
    float i01 = __fdiv_rn(__fsub_rn(__fmul_rn(k02, k21), __fmul_rn(k01, k22)), det);
    float i02 = __fdiv_rn(__fsub_rn(__fmul_rn(k01, k12), __fmul_rn(k02, k11)), det);
    float i10 = __fdiv_rn(c01, det);
    float i11 = __fdiv_rn(__fsub_rn(__fmul_rn(k00, k22), __fmul_rn(k02, k20)), det);
    float i12 = __fdiv_rn(__fsub_rn(__fmul_rn(k02, k10), __fmul_rn(k00, k12)), det);
    float i20 = __fdiv_rn(c02, det);
    float i21 = __fdiv_rn(__fsub_rn(__fmul_rn(k01, k20), __fmul_rn(k00, k21)), det);
    float i22 = __fdiv_rn(__fsub_rn(__fmul_rn(k00, k11), __fmul_rn(k01, k10)), det);

    const float* E = Emat + (size_t)bn * 16;
    float r00 = E[0], r01 = E[1], r02 = E[2],  tx = E[3];
    float r10 = E[4], r11 = E[5], r12 = E[6],  ty = E[7];
    float r20 = E[8], r21 = E[9], r22 = E[10], tz = E[11];

    __syncthreads();   // feat_lds ready (fallback may read any h)

    float* accb = acc + (size_t)b * (BHc * BWc) * Cc;

    int h = lane;                        // geometry lane role
    float xf = (float)w;
    float yf = (float)h;

    float accv[DWAVE];
    float mval[DWAVE];                   // masked depth, lane h slot k
    int   prim[DWAVE];

    // ---- Phase 1: geometry; masked depth kept in registers ----
#pragma unroll
    for (int k = 0; k < DWAVE; ++k) {
        accv[k] = 0.0f;
        mval[k] = 0.0f;
        prim[k] = -1;
        int dg = wid + NWAVES * k;
        if (dg < Dc) {
            float db = (float)(dg + 1);          // depth bins 1..59
            float dep = 0.0f;
            if (h < Hc)
                dep = dcol[(size_t)dg * HW + (size_t)h * Wc];

            float px = __fmul_rn(xf, db);
            float py = __fmul_rn(yf, db);
            float pz = db;

            float cx = __fadd_rn(__fadd_rn(__fmul_rn(i00, px), __fmul_rn(i01, py)), __fmul_rn(i02, pz));
            float cy = __fadd_rn(__fadd_rn(__fmul_rn(i10, px), __fmul_rn(i11, py)), __fmul_rn(i12, pz));
            float cz = __fadd_rn(__fadd_rn(__fmul_rn(i20, px), __fmul_rn(i21, py)), __fmul_rn(i22, pz));

            float ex = __fadd_rn(__fadd_rn(__fadd_rn(__fmul_rn(r00, cx), __fmul_rn(r01, cy)), __fmul_rn(r02, cz)), tx);
            float ey = __fadd_rn(__fadd_rn(__fadd_rn(__fmul_rn(r10, cx), __fmul_rn(r11, cy)), __fmul_rn(r12, cz)), ty);
            float ez = __fadd_rn(__fadd_rn(__fadd_rn(__fmul_rn(r20, cx), __fmul_rn(r21, cy)), __fmul_rn(r22, cz)), tz);

            int bx = (int)(__fmul_rn(__fadd_rn(ex, 50.0f), 2.0f));
            int by = (int)(__fmul_rn(__fadd_rn(ey, 50.0f), 2.0f));

            bool valid = (h < Hc) & (bx >= 0) & (bx < BWc) & (by >= 0) & (by < BHc) & (ez > 0.0f);
            int binidx = by * BWc + bx;

            unsigned long long vm = __ballot(valid);
            if (vm != 0ULL) {
                int first = __builtin_ctzll(vm);
                int pr = __shfl(binidx, first);
                unsigned long long match = __ballot(valid && (binidx == pr));
                unsigned long long rest  = vm & ~match;
                prim[k] = pr;
                mval[k] = (valid && (binidx == pr)) ? dep : 0.0f;

                // fallback: valid h with a different bin (general case)
                while (rest) {
                    int hh2 = __builtin_ctzll(rest);
                    rest &= rest - 1;
                    int   bidx = __shfl(binidx, hh2);
                    float dv   = __shfl(dep, hh2);
                    atomicAdd(&accb[(size_t)bidx * Cc + lane],
                              __fmul_rn(feat_lds[hh2][lane], dv));
                }
            }
        }
    }

    // ---- Phase 2: dense matmul, depth broadcast via readlane (no LDS) ----
#pragma unroll
    for (int hh = 0; hh < Hc; ++hh) {
        float f = feat_lds[hh][lane];
#pragma unroll
        for (int k = 0; k < DWAVE; ++k) {
            float dk = __int_as_float(
                __builtin_amdgcn_readlane(__float_as_int(mval[k]), hh));
            accv[k] = __builtin_fmaf(f, dk, accv[k]);
        }
    }

    // ---- Phase 3: one 64-lane atomic per d ----
#pragma unroll
    for (int k = 0; k < DWAVE; ++k) {
        if (prim[k] >= 0)
            atomicAdd(&accb[(size_t)prim[k] * Cc + lane], accv[k]);
    }
}

// (B, BH*BW, C) -> (B, C, BH*BW), LDS-tiled 64x64
__global__ __launch_bounds__(256) void fp_transpose_kernel(
    const float* __restrict__ acc, float* __restrict__ out)
{
    __shared__ float tile[64][65];
    const int P = BHc * BWc;                 // 40000, divisible by 64
    int b = blockIdx.y;
    int p0 = blockIdx.x * 64;
    int tx = threadIdx.x & 63;
    int ty = threadIdx.x >> 6;               // 0..3

    const float* src = acc + (size_t)b * P * Cc;
#pragma unroll
    for (int i = 0; i < 16; ++i) {
        int row = ty * 16 + i;
        tile[row][tx] = src[(size_t)(p0 + row) * Cc + tx];
    }
    __syncthreads();
    float* dst = out + (size_t)b * Cc * P;
#pragma unroll
    for (int i = 0; i < 16; ++i) {
        int c = ty * 16 + i;
        dst[(size_t)c * P + p0 + tx] = tile[tx][c];
    }
}

extern "C" void kernel_launch(void* const* d_in, const int* in_sizes, int n_in,
                              void* d_out, int out_size, void* d_ws, size_t ws_size,
                              hipStream_t stream) {
    const float* feats = (const float*)d_in[0];
    const float* depth = (const float*)d_in[1];
    const float* Kmat  = (const float*)d_in[2];
    const float* Emat  = (const float*)d_in[3];
    float* out = (float*)d_out;

    float* acc = (float*)d_ws;

    // 1) zero accumulator
    fp_zero<<<NZ, 256, 0, stream>>>(acc);

    // 2) scatter straight from original layouts (XCD-swizzled blocks)
    fp_scatter6<<<600, 512, 0, stream>>>(feats, depth, Kmat, Emat, acc);

    // 3) transpose to output layout
    fp_transpose_kernel<<<dim3((BHc * BWc) / 64, Bc), 256, 0, stream>>>(acc, out);
}